// Round 1
// baseline (700.557 us; speedup 1.0000x reference)
//
#include <hip/hip_runtime.h>
#include <cstdint>
#include <cstddef>

typedef __attribute__((ext_vector_type(8))) short short8;
typedef __attribute__((ext_vector_type(4))) float f32x4;

#define D_MODEL 1024
#define NHEADS 16
#define DHEAD 64
#define BATCH 4
#define SEQ 2048
#define MTOK (BATCH * SEQ)

__device__ __forceinline__ unsigned short f2bf(float f) {
  union { float f; unsigned u; } v; v.f = f;
  unsigned r = v.u + 0x7fffu + ((v.u >> 16) & 1u);
  return (unsigned short)(r >> 16);
}
__device__ __forceinline__ float bf2f(unsigned short u) {
  union { unsigned u; float f; } v; v.u = ((unsigned)u) << 16;
  return v.f;
}

#define MFMA_BF16(a, b, c) __builtin_amdgcn_mfma_f32_16x16x32_bf16(a, b, c, 0, 0, 0)

// ---------------- fp32 -> bf16 conversion (weights) ----------------
__global__ __launch_bounds__(256) void f32_to_bf16(const float* __restrict__ src,
                                                   unsigned short* __restrict__ dst, int n4) {
  int i = blockIdx.x * 256 + threadIdx.x;
  if (i >= n4) return;
  float4 v = ((const float4*)src)[i];
  ushort4 o;
  o.x = f2bf(v.x); o.y = f2bf(v.y); o.z = f2bf(v.z); o.w = f2bf(v.w);
  ((ushort4*)dst)[i] = o;
}

// ---------------- LayerNorm: fp32 in -> bf16 out ----------------
__global__ __launch_bounds__(256) void ln_fwd(const float* __restrict__ x, const float* __restrict__ g,
                                              const float* __restrict__ b,
                                              unsigned short* __restrict__ out) {
  const int row = blockIdx.x, t = threadIdx.x;
  float4 v = *(const float4*)(x + (size_t)row * D_MODEL + t * 4);
  float s = v.x + v.y + v.z + v.w;
  float s2 = v.x * v.x + v.y * v.y + v.z * v.z + v.w * v.w;
#pragma unroll
  for (int m = 1; m < 64; m <<= 1) { s += __shfl_xor(s, m); s2 += __shfl_xor(s2, m); }
  __shared__ float red[8];
  int wv = t >> 6;
  if ((t & 63) == 0) { red[wv] = s; red[4 + wv] = s2; }
  __syncthreads();
  s = red[0] + red[1] + red[2] + red[3];
  s2 = red[4] + red[5] + red[6] + red[7];
  float mu = s * (1.f / D_MODEL);
  float var = s2 * (1.f / D_MODEL) - mu * mu;
  float rs = rsqrtf(var + 1e-5f);
  float4 gg = *(const float4*)(g + t * 4);
  float4 bb = *(const float4*)(b + t * 4);
  ushort4 o;
  o.x = f2bf((v.x - mu) * rs * gg.x + bb.x);
  o.y = f2bf((v.y - mu) * rs * gg.y + bb.y);
  o.z = f2bf((v.z - mu) * rs * gg.z + bb.z);
  o.w = f2bf((v.w - mu) * rs * gg.w + bb.w);
  *(ushort4*)(out + (size_t)row * D_MODEL + t * 4) = o;
}

// ---------------- GEMM: C[M,N] = A[M,K] * B[N,K]^T  (bf16 MFMA) ----------------
// EPI: 0 = bf16 store, 1 = fp32 store of (R + acc), 2 = bf16 store of relu(acc)
template <int EPI>
__global__ __launch_bounds__(256) void gemm_bt(const unsigned short* __restrict__ A,
                                               const unsigned short* __restrict__ B,
                                               const float* __restrict__ R,
                                               void* __restrict__ Cout, int M, int N, int K) {
  constexpr int BM = 128, BN = 128, BK = 32, LDT = 40;  // padded LDS stride
  __shared__ unsigned short lA[BM * LDT], lB[BN * LDT];
  const int tid = threadIdx.x, lane = tid & 63, wave = tid >> 6;
  const int bm = blockIdx.y * BM, bn = blockIdx.x * BN;
  const int wr = wave >> 1, wc = wave & 1;
  f32x4 acc[4][4] = {};
  const int srow = tid >> 2, scol = (tid & 3) * 8;
  const unsigned short* gA = A + (size_t)(bm + srow) * K + scol;
  const unsigned short* gB = B + (size_t)(bn + srow) * K + scol;
  unsigned short* wAp = lA + srow * LDT + scol;
  unsigned short* wBp = lB + srow * LDT + scol;
  short8 ra0 = *(const short8*)gA;
  short8 ra1 = *(const short8*)(gA + (size_t)64 * K);
  short8 rb0 = *(const short8*)gB;
  short8 rb1 = *(const short8*)(gB + (size_t)64 * K);
  const int nk = K / BK;
  for (int kt = 0; kt < nk; ++kt) {
    *(short8*)wAp = ra0;
    *(short8*)(wAp + 64 * LDT) = ra1;
    *(short8*)wBp = rb0;
    *(short8*)(wBp + 64 * LDT) = rb1;
    __syncthreads();
    if (kt + 1 < nk) {  // prefetch next K-tile into regs; overlaps with MFMA below
      const unsigned short* pA = gA + (kt + 1) * BK;
      const unsigned short* pB = gB + (kt + 1) * BK;
      ra0 = *(const short8*)pA;
      ra1 = *(const short8*)(pA + (size_t)64 * K);
      rb0 = *(const short8*)pB;
      rb1 = *(const short8*)(pB + (size_t)64 * K);
    }
    const int ko = (lane >> 4) * 8;
    short8 af[4], bfr[4];
#pragma unroll
    for (int m = 0; m < 4; ++m)
      af[m] = *(const short8*)(lA + (wr * 64 + m * 16 + (lane & 15)) * LDT + ko);
#pragma unroll
    for (int n = 0; n < 4; ++n)
      bfr[n] = *(const short8*)(lB + (wc * 64 + n * 16 + (lane & 15)) * LDT + ko);
#pragma unroll
    for (int m = 0; m < 4; ++m)
#pragma unroll
      for (int n = 0; n < 4; ++n) acc[m][n] = MFMA_BF16(af[m], bfr[n], acc[m][n]);
    __syncthreads();
  }
  const int r0 = bm + wr * 64 + (lane >> 4) * 4;
  const int c0 = bn + wc * 64 + (lane & 15);
#pragma unroll
  for (int m = 0; m < 4; ++m)
#pragma unroll
    for (int n = 0; n < 4; ++n) {
#pragma unroll
      for (int r = 0; r < 4; ++r) {
        size_t off = (size_t)(r0 + m * 16 + r) * N + (c0 + n * 16);
        float v = acc[m][n][r];
        if (EPI == 0) ((unsigned short*)Cout)[off] = f2bf(v);
        else if (EPI == 1) ((float*)Cout)[off] = R[off] + v;
        else ((unsigned short*)Cout)[off] = f2bf(fmaxf(v, 0.f));
      }
    }
}

// ---------------- prep: l2-normalize q,k in place; transpose v -> Vt[b,h,d,n] ----------------
__global__ __launch_bounds__(256) void prep_qkv(unsigned short* __restrict__ qkv,
                                                unsigned short* __restrict__ vt) {
  __shared__ unsigned short tile[64][80];
  const int blk = blockIdx.x;
  const int ntile = blk & 31, h = (blk >> 5) & 15, b = blk >> 9;
  const int t = threadIdx.x;
  const int tt = t >> 2, c4 = t & 3;  // token-in-tile, 16-elem chunk
  size_t rowbase = (size_t)(b * SEQ + ntile * 64 + tt) * 3072 + h * 64 + c4 * 16;
#pragma unroll
  for (int pk = 0; pk < 2; ++pk) {  // q then k
    unsigned short* p = qkv + rowbase + pk * 1024;
    short8 v0 = *(const short8*)p;
    short8 v1 = *(const short8*)(p + 8);
    float f[16];
#pragma unroll
    for (int j = 0; j < 8; ++j) {
      f[j] = bf2f((unsigned short)v0[j]);
      f[8 + j] = bf2f((unsigned short)v1[j]);
    }
    float ss = 0.f;
#pragma unroll
    for (int j = 0; j < 16; ++j) ss += f[j] * f[j];
    ss += __shfl_xor(ss, 1);
    ss += __shfl_xor(ss, 2);
    float sc = 1.0f / fmaxf(sqrtf(ss), 1e-12f);
    short8 o0, o1;
#pragma unroll
    for (int j = 0; j < 8; ++j) {
      o0[j] = (short)f2bf(f[j] * sc);
      o1[j] = (short)f2bf(f[8 + j] * sc);
    }
    *(short8*)p = o0;
    *(short8*)(p + 8) = o1;
  }
  const unsigned short* pv = qkv + rowbase + 2048;
  *(short8*)&tile[tt][c4 * 16] = *(const short8*)pv;
  *(short8*)&tile[tt][c4 * 16 + 8] = *(const short8*)(pv + 8);
  __syncthreads();
  const int d = tt;
  short8 o0, o1;
#pragma unroll
  for (int j = 0; j < 8; ++j) o0[j] = (short)tile[c4 * 16 + j][d];
#pragma unroll
  for (int j = 0; j < 8; ++j) o1[j] = (short)tile[c4 * 16 + 8 + j][d];
  size_t vr = (size_t)((b * NHEADS + h) * DHEAD + d) * SEQ + ntile * 64 + c4 * 16;
  *(short8*)(vt + vr) = o0;
  *(short8*)(vt + vr + 8) = o1;
}

// ---------------- flash attention: one block per (b,h,64 q-rows), 4 waves x 16 q-rows ----------------
__global__ __launch_bounds__(256) void attn_fwd(const unsigned short* __restrict__ qkv,
                                                const unsigned short* __restrict__ vt,
                                                unsigned short* __restrict__ out,
                                                const float* __restrict__ temp) {
  __shared__ unsigned short pP[4][16][40];  // per-wave P strip, padded
  const int blk = blockIdx.x;
  const int qt = blk & 31, h = (blk >> 5) & 15, b = blk >> 9;
  const int tid = threadIdx.x, lane = tid & 63, wave = tid >> 6;
  const float invT = 1.0f / temp[0];
  const int qr0 = qt * 64 + wave * 16;
  const int lo = lane & 15, g = lane >> 4;
  const unsigned short* qrow = qkv + (size_t)(b * SEQ + qr0 + lo) * 3072 + h * 64 + g * 8;
  short8 qf0 = *(const short8*)qrow;
  short8 qf1 = *(const short8*)(qrow + 32);
  const unsigned short* kbase = qkv + (size_t)(b * SEQ) * 3072 + 1024 + h * 64 + g * 8;
  const unsigned short* vbase = vt + (size_t)((b * NHEADS + h) * DHEAD) * SEQ + g * 8;
  f32x4 o[4] = {};
  float mrow[4] = {-1e30f, -1e30f, -1e30f, -1e30f};
  float lrow[4] = {0.f, 0.f, 0.f, 0.f};
  const f32x4 fzero = {};
  for (int k0 = 0; k0 < SEQ; k0 += 32) {
    f32x4 s[2];
#pragma unroll
    for (int jt = 0; jt < 2; ++jt) {
      const unsigned short* kr = kbase + (size_t)(k0 + jt * 16 + lo) * 3072;
      short8 kf0 = *(const short8*)kr;
      short8 kf1 = *(const short8*)(kr + 32);
      s[jt] = MFMA_BF16(qf1, kf1, MFMA_BF16(qf0, kf0, fzero));
    }
#pragma unroll
    for (int jt = 0; jt < 2; ++jt)
#pragma unroll
      for (int r = 0; r < 4; ++r) s[jt][r] *= invT;
    float alpha[4];
#pragma unroll
    for (int r = 0; r < 4; ++r) {
      float v = fmaxf(s[0][r], s[1][r]);
      v = fmaxf(v, __shfl_xor(v, 1));
      v = fmaxf(v, __shfl_xor(v, 2));
      v = fmaxf(v, __shfl_xor(v, 4));
      v = fmaxf(v, __shfl_xor(v, 8));
      float mn = fmaxf(mrow[r], v);
      alpha[r] = __expf(mrow[r] - mn);
      mrow[r] = mn;
      float p0 = __expf(s[0][r] - mn), p1 = __expf(s[1][r] - mn);
      s[0][r] = p0;
      s[1][r] = p1;
      float rs = p0 + p1;
      rs += __shfl_xor(rs, 1);
      rs += __shfl_xor(rs, 2);
      rs += __shfl_xor(rs, 4);
      rs += __shfl_xor(rs, 8);
      lrow[r] = lrow[r] * alpha[r] + rs;
    }
#pragma unroll
    for (int c = 0; c < 4; ++c) {
      f32x4 t_ = o[c];
#pragma unroll
      for (int r = 0; r < 4; ++r) t_[r] *= alpha[r];
      o[c] = t_;
    }
    // D-layout P -> LDS -> A-layout fragment (wave-private strip, no barrier needed)
#pragma unroll
    for (int r = 0; r < 4; ++r) {
      pP[wave][g * 4 + r][lo] = f2bf(s[0][r]);
      pP[wave][g * 4 + r][16 + lo] = f2bf(s[1][r]);
    }
    short8 pa = *(const short8*)&pP[wave][lo][g * 8];
#pragma unroll
    for (int c = 0; c < 4; ++c) {
      short8 vb = *(const short8*)(vbase + (size_t)(c * 16 + lo) * SEQ + k0);
      o[c] = MFMA_BF16(pa, vb, o[c]);
    }
  }
#pragma unroll
  for (int r = 0; r < 4; ++r) lrow[r] = 1.0f / lrow[r];
#pragma unroll
  for (int c = 0; c < 4; ++c)
#pragma unroll
    for (int r = 0; r < 4; ++r) {
      size_t off = (size_t)(b * SEQ + qr0 + g * 4 + r) * D_MODEL + h * 64 + c * 16 + lo;
      out[off] = f2bf(o[c][r] * lrow[r]);
    }
}

// ---------------- host launch ----------------
extern "C" void kernel_launch(void* const* d_in, const int* in_sizes, int n_in, void* d_out,
                              int out_size, void* d_ws, size_t ws_size, hipStream_t stream) {
  const float* x = (const float*)d_in[0];
  const float* w_qkv = (const float*)d_in[1];
  const float* w_out = (const float*)d_in[2];
  const float* w_ffn1 = (const float*)d_in[3];
  const float* w_ffn2 = (const float*)d_in[4];
  const float* g1 = (const float*)d_in[5];
  const float* b1 = (const float*)d_in[6];
  const float* g2 = (const float*)d_in[7];
  const float* b2 = (const float*)d_in[8];
  const float* temp = (const float*)d_in[9];
  float* outp = (float*)d_out;

  char* ws = (char*)d_ws;
  size_t off = 0;
  auto alloc = [&](size_t bytes) {
    void* p = ws + off;
    off += (bytes + 255) & ~(size_t)255;
    return p;
  };
  unsigned short* wqkv_bf = (unsigned short*)alloc((size_t)3072 * 1024 * 2);
  unsigned short* wout_bf = (unsigned short*)alloc((size_t)1024 * 1024 * 2);
  unsigned short* wf1_bf = (unsigned short*)alloc((size_t)2048 * 1024 * 2);
  unsigned short* wf2_bf = (unsigned short*)alloc((size_t)1024 * 2048 * 2);
  unsigned short* h_bf = (unsigned short*)alloc((size_t)MTOK * 1024 * 2);   // reused for h2
  unsigned short* qkv_bf = (unsigned short*)alloc((size_t)MTOK * 3072 * 2); // reused for ffn1 out
  unsigned short* vt_bf = (unsigned short*)alloc((size_t)BATCH * NHEADS * DHEAD * SEQ * 2);
  unsigned short* ao_bf = (unsigned short*)alloc((size_t)MTOK * 1024 * 2);
  float* x2 = (float*)alloc((size_t)MTOK * 1024 * 4);

  // weight conversions
  f32_to_bf16<<<(3072 * 1024 / 4 + 255) / 256, 256, 0, stream>>>(w_qkv, wqkv_bf, 3072 * 1024 / 4);
  f32_to_bf16<<<(1024 * 1024 / 4 + 255) / 256, 256, 0, stream>>>(w_out, wout_bf, 1024 * 1024 / 4);
  f32_to_bf16<<<(2048 * 1024 / 4 + 255) / 256, 256, 0, stream>>>(w_ffn1, wf1_bf, 2048 * 1024 / 4);
  f32_to_bf16<<<(1024 * 2048 / 4 + 255) / 256, 256, 0, stream>>>(w_ffn2, wf2_bf, 1024 * 2048 / 4);

  // LN1
  ln_fwd<<<MTOK, 256, 0, stream>>>(x, g1, b1, h_bf);
  // qkv = h @ w_qkv^T
  gemm_bt<0><<<dim3(3072 / 128, MTOK / 128), 256, 0, stream>>>(h_bf, wqkv_bf, nullptr,
                                                               (void*)qkv_bf, MTOK, 3072, 1024);
  // l2norm q,k; build Vt
  prep_qkv<<<BATCH * NHEADS * (SEQ / 64), 256, 0, stream>>>(qkv_bf, vt_bf);
  // attention
  attn_fwd<<<BATCH * NHEADS * (SEQ / 64), 256, 0, stream>>>(qkv_bf, vt_bf, ao_bf, temp);
  // x2 = x + attn_out @ w_out^T
  gemm_bt<1><<<dim3(1024 / 128, MTOK / 128), 256, 0, stream>>>(ao_bf, wout_bf, x, (void*)x2, MTOK,
                                                               1024, 1024);
  // LN2
  ln_fwd<<<MTOK, 256, 0, stream>>>(x2, g2, b2, h_bf);
  // ffn1 = relu(h2 @ w_ffn1^T)  (reuse qkv buffer)
  gemm_bt<2><<<dim3(2048 / 128, MTOK / 128), 256, 0, stream>>>(h_bf, wf1_bf, nullptr,
                                                               (void*)qkv_bf, MTOK, 2048, 1024);
  // out = x2 + ffn1 @ w_ffn2^T
  gemm_bt<1><<<dim3(1024 / 128, MTOK / 128), 256, 0, stream>>>(qkv_bf, wf2_bf, x2, (void*)outp,
                                                               MTOK, 1024, 2048);
}

// Round 2
// 442.118 us; speedup vs baseline: 1.5845x; 1.5845x over previous
//
#include <hip/hip_runtime.h>
#include <cstdint>
#include <cstddef>

typedef __attribute__((ext_vector_type(8))) short short8;
typedef __attribute__((ext_vector_type(4))) float f32x4;

#define D_MODEL 1024
#define NHEADS 16
#define DHEAD 64
#define BATCH 4
#define SEQ 2048
#define MTOK (BATCH * SEQ)

__device__ __forceinline__ unsigned short f2bf(float f) {
  union { float f; unsigned u; } v; v.f = f;
  unsigned r = v.u + 0x7fffu + ((v.u >> 16) & 1u);
  return (unsigned short)(r >> 16);
}
__device__ __forceinline__ float bf2f(unsigned short u) {
  union { unsigned u; float f; } v; v.u = ((unsigned)u) << 16;
  return v.f;
}

#define MFMA_BF16(a, b, c) __builtin_amdgcn_mfma_f32_16x16x32_bf16(a, b, c, 0, 0, 0)

// ---------------- fp32 -> bf16 conversion (weights) ----------------
__global__ __launch_bounds__(256) void f32_to_bf16(const float* __restrict__ src,
                                                   unsigned short* __restrict__ dst, int n4) {
  int i = blockIdx.x * 256 + threadIdx.x;
  if (i >= n4) return;
  float4 v = ((const float4*)src)[i];
  ushort4 o;
  o.x = f2bf(v.x); o.y = f2bf(v.y); o.z = f2bf(v.z); o.w = f2bf(v.w);
  ((ushort4*)dst)[i] = o;
}

// ---------------- LayerNorm: fp32 in -> bf16 out ----------------
__global__ __launch_bounds__(256) void ln_fwd(const float* __restrict__ x, const float* __restrict__ g,
                                              const float* __restrict__ b,
                                              unsigned short* __restrict__ out) {
  const int row = blockIdx.x, t = threadIdx.x;
  float4 v = *(const float4*)(x + (size_t)row * D_MODEL + t * 4);
  float s = v.x + v.y + v.z + v.w;
  float s2 = v.x * v.x + v.y * v.y + v.z * v.z + v.w * v.w;
#pragma unroll
  for (int m = 1; m < 64; m <<= 1) { s += __shfl_xor(s, m); s2 += __shfl_xor(s2, m); }
  __shared__ float red[8];
  int wv = t >> 6;
  if ((t & 63) == 0) { red[wv] = s; red[4 + wv] = s2; }
  __syncthreads();
  s = red[0] + red[1] + red[2] + red[3];
  s2 = red[4] + red[5] + red[6] + red[7];
  float mu = s * (1.f / D_MODEL);
  float var = s2 * (1.f / D_MODEL) - mu * mu;
  float rs = rsqrtf(var + 1e-5f);
  float4 gg = *(const float4*)(g + t * 4);
  float4 bb = *(const float4*)(b + t * 4);
  ushort4 o;
  o.x = f2bf((v.x - mu) * rs * gg.x + bb.x);
  o.y = f2bf((v.y - mu) * rs * gg.y + bb.y);
  o.z = f2bf((v.z - mu) * rs * gg.z + bb.z);
  o.w = f2bf((v.w - mu) * rs * gg.w + bb.w);
  *(ushort4*)(out + (size_t)row * D_MODEL + t * 4) = o;
}

// ---------------- GEMM: C[M,N] = A[M,K] * B[N,K]^T  (bf16 MFMA) ----------------
// EPI: 0 = bf16 store, 1 = fp32 store of (R + acc), 2 = bf16 store of relu(acc)
template <int EPI>
__global__ __launch_bounds__(256) void gemm_bt(const unsigned short* __restrict__ A,
                                               const unsigned short* __restrict__ B,
                                               const float* __restrict__ R,
                                               void* __restrict__ Cout, int M, int N, int K) {
  constexpr int BM = 128, BN = 128, BK = 32, LDT = 40;  // padded LDS stride
  __shared__ unsigned short lA[BM * LDT], lB[BN * LDT];
  const int tid = threadIdx.x, lane = tid & 63, wave = tid >> 6;
  const int bm = blockIdx.y * BM, bn = blockIdx.x * BN;
  const int wr = wave >> 1, wc = wave & 1;
  f32x4 acc[4][4] = {};
  const int srow = tid >> 2, scol = (tid & 3) * 8;
  const unsigned short* gA = A + (size_t)(bm + srow) * K + scol;
  const unsigned short* gB = B + (size_t)(bn + srow) * K + scol;
  unsigned short* wAp = lA + srow * LDT + scol;
  unsigned short* wBp = lB + srow * LDT + scol;
  short8 ra0 = *(const short8*)gA;
  short8 ra1 = *(const short8*)(gA + (size_t)64 * K);
  short8 rb0 = *(const short8*)gB;
  short8 rb1 = *(const short8*)(gB + (size_t)64 * K);
  const int nk = K / BK;
  for (int kt = 0; kt < nk; ++kt) {
    *(short8*)wAp = ra0;
    *(short8*)(wAp + 64 * LDT) = ra1;
    *(short8*)wBp = rb0;
    *(short8*)(wBp + 64 * LDT) = rb1;
    __syncthreads();
    if (kt + 1 < nk) {  // prefetch next K-tile into regs; overlaps with MFMA below
      const unsigned short* pA = gA + (kt + 1) * BK;
      const unsigned short* pB = gB + (kt + 1) * BK;
      ra0 = *(const short8*)pA;
      ra1 = *(const short8*)(pA + (size_t)64 * K);
      rb0 = *(const short8*)pB;
      rb1 = *(const short8*)(pB + (size_t)64 * K);
    }
    const int ko = (lane >> 4) * 8;
    short8 af[4], bfr[4];
#pragma unroll
    for (int m = 0; m < 4; ++m)
      af[m] = *(const short8*)(lA + (wr * 64 + m * 16 + (lane & 15)) * LDT + ko);
#pragma unroll
    for (int n = 0; n < 4; ++n)
      bfr[n] = *(const short8*)(lB + (wc * 64 + n * 16 + (lane & 15)) * LDT + ko);
#pragma unroll
    for (int m = 0; m < 4; ++m)
#pragma unroll
      for (int n = 0; n < 4; ++n) acc[m][n] = MFMA_BF16(af[m], bfr[n], acc[m][n]);
    __syncthreads();
  }
  const int r0 = bm + wr * 64 + (lane >> 4) * 4;
  const int c0 = bn + wc * 64 + (lane & 15);
#pragma unroll
  for (int m = 0; m < 4; ++m)
#pragma unroll
    for (int n = 0; n < 4; ++n) {
#pragma unroll
      for (int r = 0; r < 4; ++r) {
        size_t off = (size_t)(r0 + m * 16 + r) * N + (c0 + n * 16);
        float v = acc[m][n][r];
        if (EPI == 0) ((unsigned short*)Cout)[off] = f2bf(v);
        else if (EPI == 1) ((float*)Cout)[off] = R[off] + v;
        else ((unsigned short*)Cout)[off] = f2bf(fmaxf(v, 0.f));
      }
    }
}

// ---------------- prep: l2-normalize q,k in place; transpose v -> Vt[b,h,d,n] ----------------
__global__ __launch_bounds__(256) void prep_qkv(unsigned short* __restrict__ qkv,
                                                unsigned short* __restrict__ vt) {
  __shared__ unsigned short tile[64][80];
  const int blk = blockIdx.x;
  const int ntile = blk & 31, h = (blk >> 5) & 15, b = blk >> 9;
  const int t = threadIdx.x;
  const int tt = t >> 2, c4 = t & 3;  // token-in-tile, 16-elem chunk
  size_t rowbase = (size_t)(b * SEQ + ntile * 64 + tt) * 3072 + h * 64 + c4 * 16;
#pragma unroll
  for (int pk = 0; pk < 2; ++pk) {  // q then k
    unsigned short* p = qkv + rowbase + pk * 1024;
    short8 v0 = *(const short8*)p;
    short8 v1 = *(const short8*)(p + 8);
    float f[16];
#pragma unroll
    for (int j = 0; j < 8; ++j) {
      f[j] = bf2f((unsigned short)v0[j]);
      f[8 + j] = bf2f((unsigned short)v1[j]);
    }
    float ss = 0.f;
#pragma unroll
    for (int j = 0; j < 16; ++j) ss += f[j] * f[j];
    ss += __shfl_xor(ss, 1);
    ss += __shfl_xor(ss, 2);
    float sc = 1.0f / fmaxf(sqrtf(ss), 1e-12f);
    short8 o0, o1;
#pragma unroll
    for (int j = 0; j < 8; ++j) {
      o0[j] = (short)f2bf(f[j] * sc);
      o1[j] = (short)f2bf(f[8 + j] * sc);
    }
    *(short8*)p = o0;
    *(short8*)(p + 8) = o1;
  }
  const unsigned short* pv = qkv + rowbase + 2048;
  *(short8*)&tile[tt][c4 * 16] = *(const short8*)pv;
  *(short8*)&tile[tt][c4 * 16 + 8] = *(const short8*)(pv + 8);
  __syncthreads();
  const int d = tt;
  short8 o0, o1;
#pragma unroll
  for (int j = 0; j < 8; ++j) o0[j] = (short)tile[c4 * 16 + j][d];
#pragma unroll
  for (int j = 0; j < 8; ++j) o1[j] = (short)tile[c4 * 16 + 8 + j][d];
  size_t vr = (size_t)((b * NHEADS + h) * DHEAD + d) * SEQ + ntile * 64 + c4 * 16;
  *(short8*)(vt + vr) = o0;
  *(short8*)(vt + vr + 8) = o1;
}

// ---------------- flash attention v2 ----------------
// 8 waves x 16 q-rows = 128 q-rows/block; KVBLK=64; K,V double-buffered in LDS
// (coalesced cooperative staging, reg-prefetch so HBM latency hides under compute).
__global__ __launch_bounds__(512) void attn_fwd2(const unsigned short* __restrict__ qkv,
                                                 const unsigned short* __restrict__ vt,
                                                 unsigned short* __restrict__ out,
                                                 const float* __restrict__ temp) {
  constexpr int LDT = 72;  // padded stride: bank-balanced for ds_read_b128, 16B-aligned rows
  __shared__ unsigned short lK[2][64 * LDT];
  __shared__ unsigned short lV[2][64 * LDT];
  __shared__ unsigned short pP[8][16 * LDT];  // per-wave P strip (D-layout -> A-layout)
  const int blk = blockIdx.x;
  const int qt = blk & 15, h = (blk >> 4) & 15, b = blk >> 8;
  const int tid = threadIdx.x, lane = tid & 63, wave = tid >> 6;
  const int lo = lane & 15, g = lane >> 4;
  const float invT = 1.0f / temp[0];
  const int qr0 = qt * 128 + wave * 16;
  // Q fragments live in registers for the whole kernel
  const unsigned short* qrow = qkv + (size_t)(b * SEQ + qr0 + lo) * 3072 + h * 64 + g * 8;
  const short8 qf0 = *(const short8*)qrow;
  const short8 qf1 = *(const short8*)(qrow + 32);
  // cooperative staging: 512 threads x 16B = one 64x64 bf16 tile per array
  const int srow = tid >> 3, scol = (tid & 7) * 8;
  const unsigned short* gK = qkv + (size_t)(b * SEQ + srow) * 3072 + 1024 + h * 64 + scol;
  const unsigned short* gV = vt + ((size_t)((b * NHEADS + h) * DHEAD) + srow) * SEQ + scol;
  short8 rk = *(const short8*)gK;
  short8 rv = *(const short8*)gV;
  *(short8*)&lK[0][srow * LDT + scol] = rk;
  *(short8*)&lV[0][srow * LDT + scol] = rv;
  f32x4 o[4] = {};
  float mrow[4] = {-1e30f, -1e30f, -1e30f, -1e30f};
  float lrow[4] = {0.f, 0.f, 0.f, 0.f};
  const f32x4 fzero = {};
  unsigned short* Pb = &pP[wave][0];
  constexpr int NT = SEQ / 64;
  for (int t = 0; t < NT; ++t) {
    __syncthreads();  // staged writes for tile t visible; all waves done with tile t-1
    const unsigned short* Kb = &lK[t & 1][0];
    const unsigned short* Vb = &lV[t & 1][0];
    if (t + 1 < NT) {  // issue next-tile global loads now; consumed at loop bottom
      rk = *(const short8*)(gK + (size_t)(t + 1) * 64 * 3072);
      rv = *(const short8*)(gV + (t + 1) * 64);
    }
    // QK^T over 64 keys: s[jt] covers keys jt*16..jt*16+15
    f32x4 s[4];
#pragma unroll
    for (int jt = 0; jt < 4; ++jt) {
      short8 kf0 = *(const short8*)(Kb + (jt * 16 + lo) * LDT + g * 8);
      short8 kf1 = *(const short8*)(Kb + (jt * 16 + lo) * LDT + 32 + g * 8);
      s[jt] = MFMA_BF16(qf1, kf1, MFMA_BF16(qf0, kf0, fzero));
    }
    // online softmax over the 64-key block (reduce across 16-lane groups)
    float alpha[4];
#pragma unroll
    for (int r = 0; r < 4; ++r) {
      float v0 = s[0][r] * invT, v1 = s[1][r] * invT, v2 = s[2][r] * invT, v3 = s[3][r] * invT;
      float mx = fmaxf(fmaxf(v0, v1), fmaxf(v2, v3));
      mx = fmaxf(mx, __shfl_xor(mx, 1));
      mx = fmaxf(mx, __shfl_xor(mx, 2));
      mx = fmaxf(mx, __shfl_xor(mx, 4));
      mx = fmaxf(mx, __shfl_xor(mx, 8));
      float mn = fmaxf(mrow[r], mx);
      alpha[r] = __expf(mrow[r] - mn);
      mrow[r] = mn;
      v0 = __expf(v0 - mn); v1 = __expf(v1 - mn); v2 = __expf(v2 - mn); v3 = __expf(v3 - mn);
      s[0][r] = v0; s[1][r] = v1; s[2][r] = v2; s[3][r] = v3;
      float rs = v0 + v1 + v2 + v3;
      rs += __shfl_xor(rs, 1);
      rs += __shfl_xor(rs, 2);
      rs += __shfl_xor(rs, 4);
      rs += __shfl_xor(rs, 8);
      lrow[r] = lrow[r] * alpha[r] + rs;
    }
    // P (D-layout) -> wave-private LDS strip -> A-layout fragments
#pragma unroll
    for (int r = 0; r < 4; ++r)
#pragma unroll
      for (int jt = 0; jt < 4; ++jt) Pb[(g * 4 + r) * LDT + jt * 16 + lo] = f2bf(s[jt][r]);
#pragma unroll
    for (int c = 0; c < 4; ++c)
#pragma unroll
      for (int r = 0; r < 4; ++r) o[c][r] *= alpha[r];
    short8 pa0 = *(const short8*)(Pb + lo * LDT + g * 8);
    short8 pa1 = *(const short8*)(Pb + lo * LDT + 32 + g * 8);
    // PV: o[c] covers output dims c*16..c*16+15
#pragma unroll
    for (int c = 0; c < 4; ++c) {
      short8 vb0 = *(const short8*)(Vb + (c * 16 + lo) * LDT + g * 8);
      short8 vb1 = *(const short8*)(Vb + (c * 16 + lo) * LDT + 32 + g * 8);
      o[c] = MFMA_BF16(pa1, vb1, MFMA_BF16(pa0, vb0, o[c]));
    }
    if (t + 1 < NT) {  // write prefetched tile into the other buffer
      *(short8*)&lK[(t + 1) & 1][srow * LDT + scol] = rk;
      *(short8*)&lV[(t + 1) & 1][srow * LDT + scol] = rv;
    }
  }
#pragma unroll
  for (int r = 0; r < 4; ++r) lrow[r] = 1.0f / lrow[r];
#pragma unroll
  for (int c = 0; c < 4; ++c)
#pragma unroll
    for (int r = 0; r < 4; ++r) {
      size_t off2 = (size_t)(b * SEQ + qr0 + g * 4 + r) * D_MODEL + h * 64 + c * 16 + lo;
      out[off2] = f2bf(o[c][r] * lrow[r]);
    }
}

// ---------------- host launch ----------------
extern "C" void kernel_launch(void* const* d_in, const int* in_sizes, int n_in, void* d_out,
                              int out_size, void* d_ws, size_t ws_size, hipStream_t stream) {
  const float* x = (const float*)d_in[0];
  const float* w_qkv = (const float*)d_in[1];
  const float* w_out = (const float*)d_in[2];
  const float* w_ffn1 = (const float*)d_in[3];
  const float* w_ffn2 = (const float*)d_in[4];
  const float* g1 = (const float*)d_in[5];
  const float* b1 = (const float*)d_in[6];
  const float* g2 = (const float*)d_in[7];
  const float* b2 = (const float*)d_in[8];
  const float* temp = (const float*)d_in[9];
  float* outp = (float*)d_out;

  char* ws = (char*)d_ws;
  size_t off = 0;
  auto alloc = [&](size_t bytes) {
    void* p = ws + off;
    off += (bytes + 255) & ~(size_t)255;
    return p;
  };
  unsigned short* wqkv_bf = (unsigned short*)alloc((size_t)3072 * 1024 * 2);
  unsigned short* wout_bf = (unsigned short*)alloc((size_t)1024 * 1024 * 2);
  unsigned short* wf1_bf = (unsigned short*)alloc((size_t)2048 * 1024 * 2);
  unsigned short* wf2_bf = (unsigned short*)alloc((size_t)1024 * 2048 * 2);
  unsigned short* h_bf = (unsigned short*)alloc((size_t)MTOK * 1024 * 2);   // reused for h2
  unsigned short* qkv_bf = (unsigned short*)alloc((size_t)MTOK * 3072 * 2); // reused for ffn1 out
  unsigned short* vt_bf = (unsigned short*)alloc((size_t)BATCH * NHEADS * DHEAD * SEQ * 2);
  unsigned short* ao_bf = (unsigned short*)alloc((size_t)MTOK * 1024 * 2);
  float* x2 = (float*)alloc((size_t)MTOK * 1024 * 4);

  // weight conversions
  f32_to_bf16<<<(3072 * 1024 / 4 + 255) / 256, 256, 0, stream>>>(w_qkv, wqkv_bf, 3072 * 1024 / 4);
  f32_to_bf16<<<(1024 * 1024 / 4 + 255) / 256, 256, 0, stream>>>(w_out, wout_bf, 1024 * 1024 / 4);
  f32_to_bf16<<<(2048 * 1024 / 4 + 255) / 256, 256, 0, stream>>>(w_ffn1, wf1_bf, 2048 * 1024 / 4);
  f32_to_bf16<<<(1024 * 2048 / 4 + 255) / 256, 256, 0, stream>>>(w_ffn2, wf2_bf, 1024 * 2048 / 4);

  // LN1
  ln_fwd<<<MTOK, 256, 0, stream>>>(x, g1, b1, h_bf);
  // qkv = h @ w_qkv^T
  gemm_bt<0><<<dim3(3072 / 128, MTOK / 128), 256, 0, stream>>>(h_bf, wqkv_bf, nullptr,
                                                               (void*)qkv_bf, MTOK, 3072, 1024);
  // l2norm q,k; build Vt
  prep_qkv<<<BATCH * NHEADS * (SEQ / 64), 256, 0, stream>>>(qkv_bf, vt_bf);
  // attention
  attn_fwd2<<<BATCH * NHEADS * (SEQ / 128), 512, 0, stream>>>(qkv_bf, vt_bf, ao_bf, temp);
  // x2 = x + attn_out @ w_out^T
  gemm_bt<1><<<dim3(1024 / 128, MTOK / 128), 256, 0, stream>>>(ao_bf, wout_bf, x, (void*)x2, MTOK,
                                                               1024, 1024);
  // LN2
  ln_fwd<<<MTOK, 256, 0, stream>>>(x2, g2, b2, h_bf);
  // ffn1 = relu(h2 @ w_ffn1^T)  (reuse qkv buffer)
  gemm_bt<2><<<dim3(2048 / 128, MTOK / 128), 256, 0, stream>>>(h_bf, wf1_bf, nullptr,
                                                               (void*)qkv_bf, MTOK, 2048, 1024);
  // out = x2 + ffn1 @ w_ffn2^T
  gemm_bt<1><<<dim3(1024 / 128, MTOK / 128), 256, 0, stream>>>(qkv_bf, wf2_bf, x2, (void*)outp,
                                                               MTOK, 1024, 2048);
}

// Round 3
// 399.821 us; speedup vs baseline: 1.7522x; 1.1058x over previous
//
#include <hip/hip_runtime.h>
#include <cstdint>
#include <cstddef>

typedef __attribute__((ext_vector_type(8))) short short8;
typedef __attribute__((ext_vector_type(4))) float f32x4;

#define D_MODEL 1024
#define NHEADS 16
#define DHEAD 64
#define BATCH 4
#define SEQ 2048
#define MTOK (BATCH * SEQ)

__device__ __forceinline__ unsigned short f2bf(float f) {
  union { float f; unsigned u; } v; v.f = f;
  unsigned r = v.u + 0x7fffu + ((v.u >> 16) & 1u);
  return (unsigned short)(r >> 16);
}
__device__ __forceinline__ float bf2f(unsigned short u) {
  union { unsigned u; float f; } v; v.u = ((unsigned)u) << 16;
  return v.f;
}
__device__ __forceinline__ unsigned cvt_pk_bf16(float a, float b) {
  unsigned u;
  asm("v_cvt_pk_bf16_f32 %0, %1, %2" : "=v"(u) : "v"(a), "v"(b));
  return u;
}

#define MFMA_BF16(a, b, c) __builtin_amdgcn_mfma_f32_16x16x32_bf16(a, b, c, 0, 0, 0)

// ---------------- fp32 -> bf16 conversion (weights) ----------------
__global__ __launch_bounds__(256) void f32_to_bf16(const float* __restrict__ src,
                                                   unsigned short* __restrict__ dst, int n4) {
  int i = blockIdx.x * 256 + threadIdx.x;
  if (i >= n4) return;
  float4 v = ((const float4*)src)[i];
  ushort4 o;
  o.x = f2bf(v.x); o.y = f2bf(v.y); o.z = f2bf(v.z); o.w = f2bf(v.w);
  ((ushort4*)dst)[i] = o;
}

// ---------------- LayerNorm: fp32 in -> bf16 out ----------------
__global__ __launch_bounds__(256) void ln_fwd(const float* __restrict__ x, const float* __restrict__ g,
                                              const float* __restrict__ b,
                                              unsigned short* __restrict__ out) {
  const int row = blockIdx.x, t = threadIdx.x;
  float4 v = *(const float4*)(x + (size_t)row * D_MODEL + t * 4);
  float s = v.x + v.y + v.z + v.w;
  float s2 = v.x * v.x + v.y * v.y + v.z * v.z + v.w * v.w;
#pragma unroll
  for (int m = 1; m < 64; m <<= 1) { s += __shfl_xor(s, m); s2 += __shfl_xor(s2, m); }
  __shared__ float red[8];
  int wv = t >> 6;
  if ((t & 63) == 0) { red[wv] = s; red[4 + wv] = s2; }
  __syncthreads();
  s = red[0] + red[1] + red[2] + red[3];
  s2 = red[4] + red[5] + red[6] + red[7];
  float mu = s * (1.f / D_MODEL);
  float var = s2 * (1.f / D_MODEL) - mu * mu;
  float rs = rsqrtf(var + 1e-5f);
  float4 gg = *(const float4*)(g + t * 4);
  float4 bb = *(const float4*)(b + t * 4);
  ushort4 o;
  o.x = f2bf((v.x - mu) * rs * gg.x + bb.x);
  o.y = f2bf((v.y - mu) * rs * gg.y + bb.y);
  o.z = f2bf((v.z - mu) * rs * gg.z + bb.z);
  o.w = f2bf((v.w - mu) * rs * gg.w + bb.w);
  *(ushort4*)(out + (size_t)row * D_MODEL + t * 4) = o;
}

// ---------------- GEMM: C[M,N] = A[M,K] * B[N,K]^T  (bf16 MFMA) ----------------
// EPI: 0 = bf16 store, 1 = fp32 store of (R + acc), 2 = bf16 store of relu(acc)
template <int EPI>
__global__ __launch_bounds__(256) void gemm_bt(const unsigned short* __restrict__ A,
                                               const unsigned short* __restrict__ B,
                                               const float* __restrict__ R,
                                               void* __restrict__ Cout, int M, int N, int K) {
  constexpr int BM = 128, BN = 128, BK = 32, LDT = 40;  // padded LDS stride
  __shared__ unsigned short lA[BM * LDT], lB[BN * LDT];
  const int tid = threadIdx.x, lane = tid & 63, wave = tid >> 6;
  const int bm = blockIdx.y * BM, bn = blockIdx.x * BN;
  const int wr = wave >> 1, wc = wave & 1;
  f32x4 acc[4][4] = {};
  const int srow = tid >> 2, scol = (tid & 3) * 8;
  const unsigned short* gA = A + (size_t)(bm + srow) * K + scol;
  const unsigned short* gB = B + (size_t)(bn + srow) * K + scol;
  unsigned short* wAp = lA + srow * LDT + scol;
  unsigned short* wBp = lB + srow * LDT + scol;
  short8 ra0 = *(const short8*)gA;
  short8 ra1 = *(const short8*)(gA + (size_t)64 * K);
  short8 rb0 = *(const short8*)gB;
  short8 rb1 = *(const short8*)(gB + (size_t)64 * K);
  const int nk = K / BK;
  for (int kt = 0; kt < nk; ++kt) {
    *(short8*)wAp = ra0;
    *(short8*)(wAp + 64 * LDT) = ra1;
    *(short8*)wBp = rb0;
    *(short8*)(wBp + 64 * LDT) = rb1;
    __syncthreads();
    if (kt + 1 < nk) {  // prefetch next K-tile into regs; overlaps with MFMA below
      const unsigned short* pA = gA + (kt + 1) * BK;
      const unsigned short* pB = gB + (kt + 1) * BK;
      ra0 = *(const short8*)pA;
      ra1 = *(const short8*)(pA + (size_t)64 * K);
      rb0 = *(const short8*)pB;
      rb1 = *(const short8*)(pB + (size_t)64 * K);
    }
    const int ko = (lane >> 4) * 8;
    short8 af[4], bfr[4];
#pragma unroll
    for (int m = 0; m < 4; ++m)
      af[m] = *(const short8*)(lA + (wr * 64 + m * 16 + (lane & 15)) * LDT + ko);
#pragma unroll
    for (int n = 0; n < 4; ++n)
      bfr[n] = *(const short8*)(lB + (wc * 64 + n * 16 + (lane & 15)) * LDT + ko);
#pragma unroll
    for (int m = 0; m < 4; ++m)
#pragma unroll
      for (int n = 0; n < 4; ++n) acc[m][n] = MFMA_BF16(af[m], bfr[n], acc[m][n]);
    __syncthreads();
  }
  const int r0 = bm + wr * 64 + (lane >> 4) * 4;
  const int c0 = bn + wc * 64 + (lane & 15);
#pragma unroll
  for (int m = 0; m < 4; ++m)
#pragma unroll
    for (int n = 0; n < 4; ++n) {
#pragma unroll
      for (int r = 0; r < 4; ++r) {
        size_t off = (size_t)(r0 + m * 16 + r) * N + (c0 + n * 16);
        float v = acc[m][n][r];
        if (EPI == 0) ((unsigned short*)Cout)[off] = f2bf(v);
        else if (EPI == 1) ((float*)Cout)[off] = R[off] + v;
        else ((unsigned short*)Cout)[off] = f2bf(fmaxf(v, 0.f));
      }
    }
}

// ---------------- prep: l2-normalize q (x invT), k in place; transpose v -> Vt[b,h,d,n] ----------------
__global__ __launch_bounds__(256) void prep_qkv(unsigned short* __restrict__ qkv,
                                                unsigned short* __restrict__ vt,
                                                const float* __restrict__ temp) {
  __shared__ unsigned short tile[64][80];
  const int blk = blockIdx.x;
  const int ntile = blk & 31, h = (blk >> 5) & 15, b = blk >> 9;
  const int t = threadIdx.x;
  const float invT = 1.0f / temp[0];
  const int tt = t >> 2, c4 = t & 3;  // token-in-tile, 16-elem chunk
  size_t rowbase = (size_t)(b * SEQ + ntile * 64 + tt) * 3072 + h * 64 + c4 * 16;
#pragma unroll
  for (int pk = 0; pk < 2; ++pk) {  // q then k
    unsigned short* p = qkv + rowbase + pk * 1024;
    short8 v0 = *(const short8*)p;
    short8 v1 = *(const short8*)(p + 8);
    float f[16];
#pragma unroll
    for (int j = 0; j < 8; ++j) {
      f[j] = bf2f((unsigned short)v0[j]);
      f[8 + j] = bf2f((unsigned short)v1[j]);
    }
    float ss = 0.f;
#pragma unroll
    for (int j = 0; j < 16; ++j) ss += f[j] * f[j];
    ss += __shfl_xor(ss, 1);
    ss += __shfl_xor(ss, 2);
    float sc = 1.0f / fmaxf(sqrtf(ss), 1e-12f);
    if (pk == 0) sc *= invT;  // fold 1/temperature into q
    short8 o0, o1;
#pragma unroll
    for (int j = 0; j < 8; ++j) {
      o0[j] = (short)f2bf(f[j] * sc);
      o1[j] = (short)f2bf(f[8 + j] * sc);
    }
    *(short8*)p = o0;
    *(short8*)(p + 8) = o1;
  }
  const unsigned short* pv = qkv + rowbase + 2048;
  *(short8*)&tile[tt][c4 * 16] = *(const short8*)pv;
  *(short8*)&tile[tt][c4 * 16 + 8] = *(const short8*)(pv + 8);
  __syncthreads();
  const int d = tt;
  short8 o0, o1;
#pragma unroll
  for (int j = 0; j < 8; ++j) o0[j] = (short)tile[c4 * 16 + j][d];
#pragma unroll
  for (int j = 0; j < 8; ++j) o1[j] = (short)tile[c4 * 16 + 8 + j][d];
  size_t vr = (size_t)((b * NHEADS + h) * DHEAD + d) * SEQ + ntile * 64 + c4 * 16;
  *(short8*)(vt + vr) = o0;
  *(short8*)(vt + vr + 8) = o1;
}

// ---------------- flash attention v3: swapped-operand QK^T, in-register softmax ----------------
// 8 waves x 16 q-rows; KVBLK=64; K,V double-buffered LDS (reg-prefetch).
// mfma(K,Q): lane (g=lane>>4, lo=lane&15) holds S[k = jt*16+g*4+r][q = lo] -> softmax for one
// q-row is 16 in-reg values + xor-16/32 shuffles only. PV is also swapped (mfma(Vt,P)) so the
// output stays q = lo; P goes through a per-wave LDS strip as packed-bf16 b32 writes.
__global__ __launch_bounds__(512) void attn_fwd3(const unsigned short* __restrict__ qkv,
                                                 const unsigned short* __restrict__ vt,
                                                 unsigned short* __restrict__ out) {
  constexpr int LDT = 72;  // K/V LDS row stride (shorts)
  constexpr int LDP = 66;  // P strip row stride (shorts): <=2-way banks for b32 w / b128 r
  __shared__ unsigned short lK[2][64 * LDT];
  __shared__ unsigned short lV[2][64 * LDT];
  __shared__ unsigned short pP[8][16 * LDP];
  const int blk = blockIdx.x;
  const int qt = blk & 15, h = (blk >> 4) & 15, b = blk >> 8;
  const int tid = threadIdx.x, lane = tid & 63, wave = tid >> 6;
  const int lo = lane & 15, g = lane >> 4;
  const int qr0 = qt * 128 + wave * 16;
  // Q fragments (B-operand): lane holds Q[q=lo][d = g*8.. , +32]
  const unsigned short* qrow = qkv + (size_t)(b * SEQ + qr0 + lo) * 3072 + h * 64 + g * 8;
  const short8 qf0 = *(const short8*)qrow;
  const short8 qf1 = *(const short8*)(qrow + 32);
  // cooperative staging: 512 threads x 16B = one 64x64 bf16 tile per array
  const int srow = tid >> 3, scol = (tid & 7) * 8;
  const unsigned short* gK = qkv + (size_t)(b * SEQ + srow) * 3072 + 1024 + h * 64 + scol;
  const unsigned short* gV = vt + ((size_t)((b * NHEADS + h) * DHEAD) + srow) * SEQ + scol;
  short8 rk = *(const short8*)gK;
  short8 rv = *(const short8*)gV;
  *(short8*)&lK[0][srow * LDT + scol] = rk;
  *(short8*)&lV[0][srow * LDT + scol] = rv;
  f32x4 o[4] = {};
  float mrow = -1e30f, lrow = 0.f;
  const f32x4 fzero = {};
  unsigned short* Pb = &pP[wave][0];
  constexpr int NT = SEQ / 64;
  for (int t = 0; t < NT; ++t) {
    __syncthreads();  // staged writes for tile t visible; all waves done with tile t-1
    const unsigned short* Kb = &lK[t & 1][0];
    const unsigned short* Vb = &lV[t & 1][0];
    if (t + 1 < NT) {  // issue next-tile global loads now; consumed at loop bottom
      rk = *(const short8*)(gK + (size_t)(t + 1) * 64 * 3072);
      rv = *(const short8*)(gV + (t + 1) * 64);
    }
    // QK^T (swapped): s[jt][r] = S[k = jt*16 + g*4 + r][q = lo]   (invT pre-folded into Q)
    f32x4 s[4];
#pragma unroll
    for (int jt = 0; jt < 4; ++jt) {
      short8 kf0 = *(const short8*)(Kb + (jt * 16 + lo) * LDT + g * 8);
      short8 kf1 = *(const short8*)(Kb + (jt * 16 + lo) * LDT + 32 + g * 8);
      s[jt] = MFMA_BF16(kf1, qf1, MFMA_BF16(kf0, qf0, fzero));
    }
    // online softmax: 16 in-reg values + cross-g (xor 16/32) max; sum kept lane-partial
    float t0 = fmaxf(fmaxf(s[0][0], s[0][1]), fmaxf(s[0][2], s[0][3]));
    float t1 = fmaxf(fmaxf(s[1][0], s[1][1]), fmaxf(s[1][2], s[1][3]));
    float t2 = fmaxf(fmaxf(s[2][0], s[2][1]), fmaxf(s[2][2], s[2][3]));
    float t3 = fmaxf(fmaxf(s[3][0], s[3][1]), fmaxf(s[3][2], s[3][3]));
    float mx = fmaxf(fmaxf(t0, t1), fmaxf(t2, t3));
    mx = fmaxf(mx, __shfl_xor(mx, 16));
    mx = fmaxf(mx, __shfl_xor(mx, 32));
    const float mn = fmaxf(mrow, mx);
    const float alpha = __expf(mrow - mn);
    mrow = mn;
    float ps0 = 0.f, ps1 = 0.f;
#pragma unroll
    for (int jt = 0; jt < 4; ++jt) {
      float p0 = __expf(s[jt][0] - mn), p1 = __expf(s[jt][1] - mn);
      float p2 = __expf(s[jt][2] - mn), p3 = __expf(s[jt][3] - mn);
      s[jt][0] = p0; s[jt][1] = p1; s[jt][2] = p2; s[jt][3] = p3;
      ps0 += p0 + p1;
      ps1 += p2 + p3;
    }
    lrow = lrow * alpha + (ps0 + ps1);
    // P -> packed bf16 pairs -> wave-private strip (row = q = lo), b32 writes
#pragma unroll
    for (int jt = 0; jt < 4; ++jt) {
      unsigned u0 = cvt_pk_bf16(s[jt][0], s[jt][1]);
      unsigned u1 = cvt_pk_bf16(s[jt][2], s[jt][3]);
      *(unsigned*)(Pb + lo * LDP + jt * 16 + g * 4) = u0;
      *(unsigned*)(Pb + lo * LDP + jt * 16 + g * 4 + 2) = u1;
    }
#pragma unroll
    for (int c = 0; c < 4; ++c)
#pragma unroll
      for (int r = 0; r < 4; ++r) o[c][r] *= alpha;
    // P fragment (B-operand): lane holds P[q=lo][k = g*8.. , +32]
    short8 pb0 = *(const short8*)(Pb + lo * LDP + g * 8);
    short8 pb1 = *(const short8*)(Pb + lo * LDP + 32 + g * 8);
    // PV (swapped): o[c][r] = O[q=lo][d = c*16 + g*4 + r]
#pragma unroll
    for (int c = 0; c < 4; ++c) {
      short8 vb0 = *(const short8*)(Vb + (c * 16 + lo) * LDT + g * 8);
      short8 vb1 = *(const short8*)(Vb + (c * 16 + lo) * LDT + 32 + g * 8);
      o[c] = MFMA_BF16(vb1, pb1, MFMA_BF16(vb0, pb0, o[c]));
    }
    if (t + 1 < NT) {  // write prefetched tile into the other buffer
      *(short8*)&lK[(t + 1) & 1][srow * LDT + scol] = rk;
      *(short8*)&lV[(t + 1) & 1][srow * LDT + scol] = rv;
    }
  }
  // cross-g sum reduce (deferred), then normalize + packed stores
  lrow += __shfl_xor(lrow, 16);
  lrow += __shfl_xor(lrow, 32);
  const float rinv = 1.0f / lrow;
  unsigned short* orow = out + (size_t)(b * SEQ + qr0 + lo) * D_MODEL + h * 64 + g * 4;
#pragma unroll
  for (int c = 0; c < 4; ++c)
#pragma unroll
    for (int r = 0; r < 4; r += 2) {
      unsigned u = cvt_pk_bf16(o[c][r] * rinv, o[c][r + 1] * rinv);
      *(unsigned*)(orow + c * 16 + r) = u;
    }
}

// ---------------- host launch ----------------
extern "C" void kernel_launch(void* const* d_in, const int* in_sizes, int n_in, void* d_out,
                              int out_size, void* d_ws, size_t ws_size, hipStream_t stream) {
  const float* x = (const float*)d_in[0];
  const float* w_qkv = (const float*)d_in[1];
  const float* w_out = (const float*)d_in[2];
  const float* w_ffn1 = (const float*)d_in[3];
  const float* w_ffn2 = (const float*)d_in[4];
  const float* g1 = (const float*)d_in[5];
  const float* b1 = (const float*)d_in[6];
  const float* g2 = (const float*)d_in[7];
  const float* b2 = (const float*)d_in[8];
  const float* temp = (const float*)d_in[9];
  float* outp = (float*)d_out;

  char* ws = (char*)d_ws;
  size_t off = 0;
  auto alloc = [&](size_t bytes) {
    void* p = ws + off;
    off += (bytes + 255) & ~(size_t)255;
    return p;
  };
  unsigned short* wqkv_bf = (unsigned short*)alloc((size_t)3072 * 1024 * 2);
  unsigned short* wout_bf = (unsigned short*)alloc((size_t)1024 * 1024 * 2);
  unsigned short* wf1_bf = (unsigned short*)alloc((size_t)2048 * 1024 * 2);
  unsigned short* wf2_bf = (unsigned short*)alloc((size_t)1024 * 2048 * 2);
  unsigned short* h_bf = (unsigned short*)alloc((size_t)MTOK * 1024 * 2);   // reused for h2
  unsigned short* qkv_bf = (unsigned short*)alloc((size_t)MTOK * 3072 * 2); // reused for ffn1 out
  unsigned short* vt_bf = (unsigned short*)alloc((size_t)BATCH * NHEADS * DHEAD * SEQ * 2);
  unsigned short* ao_bf = (unsigned short*)alloc((size_t)MTOK * 1024 * 2);
  float* x2 = (float*)alloc((size_t)MTOK * 1024 * 4);

  // weight conversions
  f32_to_bf16<<<(3072 * 1024 / 4 + 255) / 256, 256, 0, stream>>>(w_qkv, wqkv_bf, 3072 * 1024 / 4);
  f32_to_bf16<<<(1024 * 1024 / 4 + 255) / 256, 256, 0, stream>>>(w_out, wout_bf, 1024 * 1024 / 4);
  f32_to_bf16<<<(2048 * 1024 / 4 + 255) / 256, 256, 0, stream>>>(w_ffn1, wf1_bf, 2048 * 1024 / 4);
  f32_to_bf16<<<(1024 * 2048 / 4 + 255) / 256, 256, 0, stream>>>(w_ffn2, wf2_bf, 1024 * 2048 / 4);

  // LN1
  ln_fwd<<<MTOK, 256, 0, stream>>>(x, g1, b1, h_bf);
  // qkv = h @ w_qkv^T
  gemm_bt<0><<<dim3(3072 / 128, MTOK / 128), 256, 0, stream>>>(h_bf, wqkv_bf, nullptr,
                                                               (void*)qkv_bf, MTOK, 3072, 1024);
  // l2norm q (x 1/temp), k; build Vt
  prep_qkv<<<BATCH * NHEADS * (SEQ / 64), 256, 0, stream>>>(qkv_bf, vt_bf, temp);
  // attention
  attn_fwd3<<<BATCH * NHEADS * (SEQ / 128), 512, 0, stream>>>(qkv_bf, vt_bf, ao_bf);
  // x2 = x + attn_out @ w_out^T
  gemm_bt<1><<<dim3(1024 / 128, MTOK / 128), 256, 0, stream>>>(ao_bf, wout_bf, x, (void*)x2, MTOK,
                                                               1024, 1024);
  // LN2
  ln_fwd<<<MTOK, 256, 0, stream>>>(x2, g2, b2, h_bf);
  // ffn1 = relu(h2 @ w_ffn1^T)  (reuse qkv buffer)
  gemm_bt<2><<<dim3(2048 / 128, MTOK / 128), 256, 0, stream>>>(h_bf, wf1_bf, nullptr,
                                                               (void*)qkv_bf, MTOK, 2048, 1024);
  // out = x2 + ffn1 @ w_ffn2^T
  gemm_bt<1><<<dim3(1024 / 128, MTOK / 128), 256, 0, stream>>>(qkv_bf, wf2_bf, x2, (void*)outp,
                                                               MTOK, 1024, 2048);
}